// Round 4
// baseline (24.250 us; speedup 1.0000x reference)
//
#include <hip/hip_runtime.h>
#include <math.h>

// Gauss2DEffect: per-pixel-sigma horizontal Gaussian blur, f32.
// x: [1,3,1024,1024], sigma: [1,1,1024,1024], out: [1,3,1024,1024]
//
// Round 4: occupancy-first. PP=2 pixels/thread -> small register footprint
// (window v[24] + 20 weight regs), target 6-8 waves/SIMD. Interior lanes
// (w0 in [12,1012]) need NO clamping: 12 aligned float2 loads per channel
// from one base pointer (offsets fold into load immediates). Edge lanes
// (11 per row) take an exec-masked scalar clamped path.
// Weights: exp(-i^2/2s^2) = q^(i^2) via recurrence, 1 exp per pixel.

#define HH 1024
#define WW 1024
#define CC 3
#define KK 10
#define PP 2

__global__ __launch_bounds__(256, 6) void gauss1d_kernel(
    const float* __restrict__ x,
    const float* __restrict__ sigma,
    float* __restrict__ out)
{
    const int t  = blockIdx.x * blockDim.x + threadIdx.x;   // segment id
    const int h  = t >> 9;                 // 512 two-pixel segments per row
    const int w0 = (t & 511) * PP;         // first pixel col (even)
    const int p0 = h * WW + w0;

    // ---- per-pixel weights (2 pixels, taps 1..10, symmetric) ----
    const float2 sg = *reinterpret_cast<const float2*>(sigma + p0);
    const float sgs[PP] = {sg.x, sg.y};
    float wt[PP][KK];          // taps 1..10 (center weight == 1)
    float invn[PP];
    #pragma unroll
    for (int p = 0; p < PP; ++p) {
        const float sig = sgs[p];
        const float inv2s2 = __builtin_amdgcn_rcpf(2.0f * sig * sig);
        const float hs = ceilf(2.0f * sig);          // half_step
        const float q = __expf(-inv2s2);             // q = exp(-1/(2s^2))
        const float q2 = q * q;
        float wp = 1.0f;   // gated w_{i-1}
        float tq = q;      // q^(2i-1)
        float norm = 1.0f;
        #pragma unroll
        for (int i = 1; i <= KK; ++i) {
            float wi = wp * tq;                      // q^(i^2) until gated
            tq *= q2;
            wi = ((float)i <= hs) ? wi : 0.0f;       // half_step gate
            wt[p][i - 1] = wi;
            norm += 2.0f * wi;
            wp = wi;
        }
        invn[p] = __builtin_amdgcn_rcpf(norm);       // norm >= 1 (center tap)
    }

    const bool fast = (w0 >= 12) && (w0 <= WW - 12);   // window fully in-bounds
    const int base = w0 - 12;                          // window start col

    #pragma unroll
    for (int c = 0; c < CC; ++c) {
        const float* __restrict__ rc = x + c * (HH * WW) + h * WW;
        float v[24];                                   // cols [w0-12, w0+11]
        if (fast) {
            const float* __restrict__ bp = rc + base;  // 8B aligned (w0 even)
            #pragma unroll
            for (int k = 0; k < 12; ++k) {
                const float2 lv = *reinterpret_cast<const float2*>(bp + 2 * k);
                v[2 * k]     = lv.x;
                v[2 * k + 1] = lv.y;
            }
        } else {
            #pragma unroll
            for (int j = 0; j < 24; ++j) {
                int col = base + j;
                col = col < 0 ? 0 : col;
                col = col > (WW - 1) ? (WW - 1) : col;
                v[j] = rc[col];
            }
        }

        float a0 = v[12];                              // center tap, weight 1
        float a1 = v[13];
        #pragma unroll
        for (int i = 1; i <= KK; ++i) {
            a0 += wt[0][i - 1] * (v[12 - i] + v[12 + i]);
            a1 += wt[1][i - 1] * (v[13 - i] + v[13 + i]);
        }
        const float2 res = {a0 * invn[0], a1 * invn[1]};
        *reinterpret_cast<float2*>(out + c * (HH * WW) + p0) = res;
    }
}

extern "C" void kernel_launch(void* const* d_in, const int* in_sizes, int n_in,
                              void* d_out, int out_size, void* d_ws, size_t ws_size,
                              hipStream_t stream) {
    const float* x = (const float*)d_in[0];
    const float* sigma = (const float*)d_in[1];
    float* out = (float*)d_out;

    const int n_threads = (HH * WW) / PP;   // 524288
    const int block = 256;
    const int grid = n_threads / block;     // 2048
    gauss1d_kernel<<<grid, block, 0, stream>>>(x, sigma, out);
}

// Round 5
// 13.575 us; speedup vs baseline: 1.7864x; 1.7864x over previous
//
#include <hip/hip_runtime.h>
#include <math.h>

// Gauss2DEffect: per-pixel-sigma horizontal Gaussian blur, f32.
// x: [1,3,1024,1024], sigma: [1,1,1024,1024], out: [1,3,1024,1024]
//
// Round 5: PP=8 pixels/thread, round-2 structure (register window, wide
// float4 loads, NO LDS). Window = 32 floats = 8 aligned float4s per channel
// -> 3.0 VMEM ops/pixel (vs 6.25 in round 2). Edge clamping costs no extra
// loads: w0 % 8 == 0 makes every window float4 either fully in-bounds,
// fully-left-oob (load at bkc=0, fix = broadcast lv.x) or fully-right-oob
// (load at bkc=1020, fix = broadcast lv.w).
// Weights: exp(-i^2/2s^2) = q^(i^2) via recurrence, 1 exp per pixel.

#define HH 1024
#define WW 1024
#define CC 3
#define KK 10
#define PP 8

__global__ __launch_bounds__(256) void gauss1d_kernel(
    const float* __restrict__ x,
    const float* __restrict__ sigma,
    float* __restrict__ out)
{
    const int t  = blockIdx.x * blockDim.x + threadIdx.x;  // 131072 threads
    const int h  = t >> 7;                  // 128 eight-pixel segments per row
    const int w0 = (t & 127) * PP;          // first pixel col, multiple of 8
    const int p0 = h * WW + w0;

    // ---- sigma: 2 aligned float4 loads ----
    const float4 sa = *reinterpret_cast<const float4*>(sigma + p0);
    const float4 sb = *reinterpret_cast<const float4*>(sigma + p0 + 4);
    const float sgs[PP] = {sa.x, sa.y, sa.z, sa.w, sb.x, sb.y, sb.z, sb.w};

    // ---- per-pixel weights (taps 1..10, symmetric; center weight == 1) ----
    float wt[PP][KK];
    float invn[PP];
    #pragma unroll
    for (int p = 0; p < PP; ++p) {
        const float sig = sgs[p];
        const float inv2s2 = __builtin_amdgcn_rcpf(2.0f * sig * sig);
        const float hs = ceilf(2.0f * sig);          // half_step
        const float q = __expf(-inv2s2);             // q = exp(-1/(2s^2))
        const float q2 = q * q;
        float wp = 1.0f;   // gated w_{i-1}
        float tq = q;      // q^(2i-1)
        float norm = 1.0f;
        #pragma unroll
        for (int i = 1; i <= KK; ++i) {
            float wi = wp * tq;                      // q^(i^2) until gated
            tq *= q2;
            wi = ((float)i <= hs) ? wi : 0.0f;       // half_step gate
            wt[p][i - 1] = wi;
            norm += 2.0f * wi;
            wp = wi;
        }
        invn[p] = __builtin_amdgcn_rcpf(norm);       // norm >= 1 (center tap)
    }

    const int base = w0 - 12;                        // window start col
    #pragma unroll
    for (int c = 0; c < CC; ++c) {
        const float* __restrict__ rc = x + c * (HH * WW) + h * WW;
        float v[PP + 2 * KK + 4];                    // 32 window floats
        #pragma unroll
        for (int k = 0; k < 8; ++k) {
            const int bk = base + 4 * k;             // bk % 4 == 0
            int bkc = bk;
            if (k < 3) bkc = bk < 0 ? 0 : bk;        // only k<3 can be left-oob
            if (k > 4) bkc = bk > (WW - 4) ? (WW - 4) : bk;  // only k>4 right-oob
            float4 lv = *reinterpret_cast<const float4*>(rc + bkc);
            if (k < 3) {                             // fully-left-clamped fix
                const bool cl = bk < 0;              // lv.x == rc[0]
                lv.y = cl ? lv.x : lv.y;
                lv.z = cl ? lv.x : lv.z;
                lv.w = cl ? lv.x : lv.w;
            }
            if (k > 4) {                             // fully-right-clamped fix
                const bool cr = bk > (WW - 4);       // lv.w == rc[1023]
                lv.x = cr ? lv.w : lv.x;
                lv.y = cr ? lv.w : lv.y;
                lv.z = cr ? lv.w : lv.z;
            }
            v[4 * k + 0] = lv.x; v[4 * k + 1] = lv.y;
            v[4 * k + 2] = lv.z; v[4 * k + 3] = lv.w;
        }

        float4 r0, r1;
        float* rp0 = reinterpret_cast<float*>(&r0);
        float* rp1 = reinterpret_cast<float*>(&r1);
        #pragma unroll
        for (int p = 0; p < PP; ++p) {
            const int o = 12 + p;                    // center index in window
            float acc = v[o];                        // center weight == 1
            #pragma unroll
            for (int i = 1; i <= KK; ++i)
                acc += wt[p][i - 1] * (v[o - i] + v[o + i]);
            const float res = acc * invn[p];
            if (p < 4) rp0[p] = res; else rp1[p - 4] = res;
        }
        float* oc = out + c * (HH * WW) + p0;
        *reinterpret_cast<float4*>(oc)     = r0;
        *reinterpret_cast<float4*>(oc + 4) = r1;
    }
}

extern "C" void kernel_launch(void* const* d_in, const int* in_sizes, int n_in,
                              void* d_out, int out_size, void* d_ws, size_t ws_size,
                              hipStream_t stream) {
    const float* x = (const float*)d_in[0];
    const float* sigma = (const float*)d_in[1];
    float* out = (float*)d_out;

    const int n_threads = (HH * WW) / PP;   // 131072
    const int block = 256;
    const int grid = n_threads / block;     // 512
    gauss1d_kernel<<<grid, block, 0, stream>>>(x, sigma, out);
}